// Round 10
// baseline (247.042 us; speedup 1.0000x reference)
//
#include <hip/hip_runtime.h>
#include <math.h>

// RPNLayer: logits = x(32768,1024) @ W(1024,16) + b; per-anchor (8) 2-class
// log-softmax CE over valid anchors; argmax + candidate mask.
//
// R9 = R7 (contiguous block streams) with the W panel FORCE-PINNED.
//   R7 post-mortem: VGPR=52 -> allocator rematerialized ~16 per-lane W
//   vector loads PER ROW (16:1 W:x traffic, L1 thrash) -> R7 never tested
//   its contiguity hypothesis. R9 pins the 64 W floats via empty asm
//   ("+v") so they cannot be rematerialized, and deepens row prefetch to 4
//   (covers ~900cy L3 latency). Everything else is R7 verbatim.
//   - Block 256 thr = 4 waves; wave s covers k=[s*256,(s+1)*256) of each
//     of the block's 32 rows; lane l owns k = s*256+l*4..+3.
//   - Block request stream = 32 rows x 4KB walked linearly = 128KB
//     contiguous (the only pattern class measured fast on this chip:
//     harness fills 6.8 TB/s, copy ubench ~3.15 TB/s read-side).
//   - Per row: 1 float4 load + 64 FMA + channel-halving fold (17 shfl) ->
//     lane 4c holds logit(row, ch c); one ds_write per 4 lanes.
//   - In-block epilogue + ticketed loss finalize (proven R7/R8).
//
// d_out (float32): [0] loss | [1..262144] predict | [262145..524288] mask
// ws: [0]=loss sum [1]=count [2]=ticket [3]=pad

#define RPB 32               // rows per block

#define PIN16(A)                                                          \
    asm volatile("" : "+v"(A[0]), "+v"(A[1]), "+v"(A[2]),  "+v"(A[3]),    \
                      "+v"(A[4]), "+v"(A[5]), "+v"(A[6]),  "+v"(A[7]),    \
                      "+v"(A[8]), "+v"(A[9]), "+v"(A[10]), "+v"(A[11]),   \
                      "+v"(A[12]),"+v"(A[13]),"+v"(A[14]), "+v"(A[15]))

__global__ __launch_bounds__(256, 4)
void rpn_main(const float* __restrict__ x, const float* __restrict__ W,
              const float* __restrict__ b, const int* __restrict__ lab,
              float* __restrict__ out, float* __restrict__ ws)
{
    __shared__ float red[4 * RPB * 16];      // 8192 B: [slice][row][ch]
    __shared__ float rsum[8];

    const int tid  = threadIdx.x;
    const int lane = tid & 63;
    const int s    = __builtin_amdgcn_readfirstlane(tid >> 6);  // k-slice
    const int row0 = blockIdx.x * RPB;

    // ---- one-time W panel: k = s*256 + lane*4 + j, all 16 ch; PINNED ----
    float w0[16], w1[16], w2[16], w3[16];
    {
        const float* wp = W + (size_t)(s * 256 + lane * 4) * 16;
#pragma unroll
        for (int q = 0; q < 4; ++q) {
            float4 a = *(const float4*)(wp +  0 + q * 4);
            float4 c = *(const float4*)(wp + 16 + q * 4);
            float4 d = *(const float4*)(wp + 32 + q * 4);
            float4 e = *(const float4*)(wp + 48 + q * 4);
            w0[4*q+0]=a.x; w0[4*q+1]=a.y; w0[4*q+2]=a.z; w0[4*q+3]=a.w;
            w1[4*q+0]=c.x; w1[4*q+1]=c.y; w1[4*q+2]=c.z; w1[4*q+3]=c.w;
            w2[4*q+0]=d.x; w2[4*q+1]=d.y; w2[4*q+2]=d.z; w2[4*q+3]=d.w;
            w3[4*q+0]=e.x; w3[4*q+1]=e.y; w3[4*q+2]=e.z; w3[4*q+3]=e.w;
        }
        PIN16(w0); PIN16(w1); PIN16(w2); PIN16(w3);
    }

    const float* xp = x + (size_t)row0 * 1024 + s * 256 + lane * 4;

    // 4-deep row prefetch (named regs; rotation collapses under unroll 4)
    float4 p0 = *(const float4*)(xp);
    float4 p1 = *(const float4*)(xp + 1024);
    float4 p2 = *(const float4*)(xp + 2048);
    float4 p3 = *(const float4*)(xp + 3072);

#pragma unroll 4
    for (int r = 0; r < RPB; ++r) {
        float4 xv = p0;
        p0 = p1; p1 = p2; p2 = p3;
        if (r + 4 < RPB) p3 = *(const float4*)(xp + (size_t)(r + 4) * 1024);

        const float xs0 = xv.x, xs1 = xv.y, xs2 = xv.z, xs3 = xv.w;
        float acc[16];
#pragma unroll
        for (int c = 0; c < 16; ++c) acc[c] = xs0 * w0[c];
#pragma unroll
        for (int c = 0; c < 16; ++c) acc[c] = fmaf(xs1, w1[c], acc[c]);
#pragma unroll
        for (int c = 0; c < 16; ++c) acc[c] = fmaf(xs2, w2[c], acc[c]);
#pragma unroll
        for (int c = 0; c < 16; ++c) acc[c] = fmaf(xs3, w3[c], acc[c]);

        // ---- channel-halving fold: ch bit3..0 <- lane bit5..2 ----
        const bool h5 = (lane & 32) != 0;
        float k8[8];
#pragma unroll
        for (int c = 0; c < 8; ++c) {
            float keep = h5 ? acc[c + 8] : acc[c];
            float send = h5 ? acc[c]     : acc[c + 8];
            k8[c] = keep + __shfl_xor(send, 32, 64);
        }
        const bool h4 = (lane & 16) != 0;
        float k4[4];
#pragma unroll
        for (int c = 0; c < 4; ++c) {
            float keep = h4 ? k8[c + 4] : k8[c];
            float send = h4 ? k8[c]     : k8[c + 4];
            k4[c] = keep + __shfl_xor(send, 16, 64);
        }
        const bool h3 = (lane & 8) != 0;
        float k2[2];
#pragma unroll
        for (int c = 0; c < 2; ++c) {
            float keep = h3 ? k4[c + 2] : k4[c];
            float send = h3 ? k4[c]     : k4[c + 2];
            k2[c] = keep + __shfl_xor(send, 8, 64);
        }
        const bool h2 = (lane & 4) != 0;
        float keep1 = h2 ? k2[1] : k2[0];
        float send1 = h2 ? k2[0] : k2[1];
        float k1 = keep1 + __shfl_xor(send1, 4, 64);
        k1 += __shfl_xor(k1, 2, 64);         // merge k sub-groups
        k1 += __shfl_xor(k1, 1, 64);

        if ((lane & 3) == 0)
            red[(s * RPB + r) * 16 + (lane >> 2)] = k1;
    }

    __syncthreads();

    // ---- in-block epilogue: thread t -> (row = t>>3, anchor = t&7) ----
    {
        const int row = tid >> 3;
        const int a   = tid & 7;
        const int gr  = row0 + row;

        const int i0 = row * 16 + 2 * a;
        float l0 = red[0 * RPB * 16 + i0]     + red[1 * RPB * 16 + i0]
                 + red[2 * RPB * 16 + i0]     + red[3 * RPB * 16 + i0]
                 + b[2 * a];
        float l1 = red[0 * RPB * 16 + i0 + 1] + red[1 * RPB * 16 + i0 + 1]
                 + red[2 * RPB * 16 + i0 + 1] + red[3 * RPB * 16 + i0 + 1]
                 + b[2 * a + 1];

        const int lb    = lab[(size_t)gr * 8 + a];
        const int pred  = (l1 > l0) ? 1 : 0;      // strict: tie -> class 0
        const int valid = (lb != -1);
        const float m   = fmaxf(l0, l1);
        const float lse = m + logf(expf(l0 - m) + expf(l1 - m));
        const float nll = lse - ((lb == 1) ? l1 : l0);
        float lsum = valid ? nll : 0.f;
        float lcnt = valid ? 1.f : 0.f;

        out[1 + (size_t)row0 * 8 + tid]          = (float)pred;
        out[1 + 262144 + (size_t)row0 * 8 + tid] = (pred && valid) ? 1.f : 0.f;

#pragma unroll
        for (int off = 32; off > 0; off >>= 1) {
            lsum += __shfl_down(lsum, off, 64);
            lcnt += __shfl_down(lcnt, off, 64);
        }
        if (lane == 0) {
            rsum[s * 2]     = lsum;
            rsum[s * 2 + 1] = lcnt;
        }
    }
    __syncthreads();

    if (tid == 0) {
        float S = rsum[0] + rsum[2] + rsum[4] + rsum[6];
        float C = rsum[1] + rsum[3] + rsum[5] + rsum[7];
        atomicAdd(&ws[0], S);
        atomicAdd(&ws[1], C);
        __threadfence();
        unsigned int old = atomicAdd((unsigned int*)(ws + 2), 1u);
        if (old == gridDim.x - 1) {              // last block finalizes loss
            float Sf = atomicAdd(&ws[0], 0.f);
            float Cf = atomicAdd(&ws[1], 0.f);
            out[0] = Sf / fmaxf(Cf, 1.f);
        }
    }
}

extern "C" void kernel_launch(void* const* d_in, const int* in_sizes, int n_in,
                              void* d_out, int out_size, void* d_ws, size_t ws_size,
                              hipStream_t stream)
{
    const float* x   = (const float*)d_in[0];   // (64,512,1024) f32
    const float* W   = (const float*)d_in[1];   // (1024,16) f32
    const float* b   = (const float*)d_in[2];   // (16,) f32
    const int*   lab = (const int*)d_in[3];     // (64,512,8) i32 in {-1,0,1}
    float* out = (float*)d_out;
    float* ws  = (float*)d_ws;

    hipMemsetAsync(ws, 0, 16, stream);
    rpn_main<<<dim3(1024), dim3(256), 0, stream>>>(x, W, b, lab, out, ws);
}